// Round 21
// baseline (818.447 us; speedup 1.0000x reference)
//
#include <hip/hip_runtime.h>
#include <math.h>

typedef unsigned int u32;
typedef unsigned long long u64;
typedef unsigned short u16;
typedef __attribute__((ext_vector_type(8))) _Float16 f16x8;  // 8 fp16 (4 VGPR)
typedef __attribute__((ext_vector_type(4))) float f32x4;

#define BIGN (-1e30f)

static constexpr int NB = 16;     // batch
static constexpr int TF = 2000;   // T_FEATS
static constexpr int TT = 400;    // T_TEXT

__device__ __forceinline__ float wsum(float v){
#pragma unroll
  for(int o=32;o;o>>=1) v += __shfl_xor(v,o,64);
  return v;
}
__device__ __forceinline__ float EXP2(float x){ return __builtin_amdgcn_exp2f(x); }
__device__ __forceinline__ float LOG2(float x){ return __builtin_amdgcn_logf(x); }
__device__ __forceinline__ float lse2b(float x, float y){
  float m = fmaxf(x,y);
  return m + LOG2(1.0f + EXP2(-fabsf(x-y)));
}
__device__ __forceinline__ float lse3b(float x, float y, float z){
  float mx = fmaxf(fmaxf(x,y),z);
  float md = __builtin_amdgcn_fmed3f(x,y,z);
  float mn = fminf(fminf(x,y),z);
  return mx + LOG2(1.0f + EXP2(md-mx) + EXP2(mn-mx));
}
__device__ __forceinline__ u16 f2h(float v){
  _Float16 h = (_Float16)v;              // round-nearest-even
  return *(u16*)&h;
}
// lane i <- lane i-1, lane 0 <- BIGN. DPP wave_shr1 (0x138): pure VALU, no LDS/lgkmcnt.
__device__ __forceinline__ float shup1(float v){
  int r = __builtin_amdgcn_update_dpp(__float_as_int(BIGN), __float_as_int(v),
                                      0x138, 0xf, 0xf, false);
  return __int_as_float(r);
}

// ---------------- gammaln tables ----------------
__global__ void k_lgt(double* lgt){
  int m = blockIdx.x*blockDim.x + threadIdx.x;
  if(m < 2432) lgt[m] = (m>=1)? lgamma((double)m) : 0.0;
}
__global__ void k_terms(const double* __restrict__ lgt, double* rowA, double* colA, double* sA){
  int i = blockIdx.x*blockDim.x + threadIdx.x;
  if(i < TF)   rowA[i] = -lgt[2401] - lgt[i+1] - lgt[2000-i] + lgt[2001];
  if(i < TT)   colA[i] =  lgt[401]  - lgt[i+2] - lgt[400-i];
  if(i < 2399) sA[i]   =  lgt[i+2]  + lgt[2399-i];
}

// ---------------- consolidated prep: 5 weight packs + txt cvt + zpad(tout1,out1) ----------------
__device__ __forceinline__ void packf(const float* __restrict__ w, u16* __restrict__ dst,
    int CIN, int KW, int i){
  int k = i % KW;
  int c = (i / KW) % CIN;
  int o = i / (KW*CIN);
  dst[((size_t)k*256 + o)*CIN + c] = f2h(w[i]);
}
__device__ __forceinline__ void cvtp(const float* __restrict__ src, u16* __restrict__ dst,
    int P, int C, int i){
  int c = i % C;
  int p = (i / C) % (P+2);
  int b = i / (C*(P+2));
  float v = 0.f;
  if(p>=1 && p<=P) v = src[((size_t)b*P + (p-1))*C + c];
  dst[i] = f2h(v);
}
__device__ __forceinline__ void zpr(u16* __restrict__ buf, int P, int j){
  int c = j % 256;
  int s = (j / 256) & 1;
  int b = j / 512;
  buf[((size_t)b*(P+2) + (s? P+1 : 0))*256 + c] = 0;
}
__global__ __launch_bounds__(256) void prep1_k(
    const float* __restrict__ fw1, const float* __restrict__ fw2, const float* __restrict__ fw3,
    const float* __restrict__ tw1, const float* __restrict__ tw2, const float* __restrict__ txt,
    u16* fw1p, u16* fw2p, u16* fw3p, u16* tw1p, u16* tw2p,
    u16* inbfT, u16* tout1, u16* out1){
  constexpr int N = 393216+196608+65536+196608+65536+1646592+8192+8192;
  for(int i = blockIdx.x*256 + threadIdx.x; i < N; i += gridDim.x*256){
    int j = i;
    if(j < 393216){ packf(fw1, fw1p, 512, 3, j); continue; } j -= 393216;
    if(j < 196608){ packf(fw2, fw2p, 256, 3, j); continue; } j -= 196608;
    if(j < 65536) { packf(fw3, fw3p, 256, 1, j); continue; } j -= 65536;
    if(j < 196608){ packf(tw1, tw1p, 256, 3, j); continue; } j -= 196608;
    if(j < 65536) { packf(tw2, tw2p, 256, 1, j); continue; } j -= 65536;
    if(j < 1646592){ cvtp(txt, inbfT, TT, 256, j); continue; } j -= 1646592;
    if(j < 8192) { zpr(tout1, TT, j); continue; } j -= 8192;
    zpr(out1, TF, j);
  }
}

// ---------------- fp32 -> padded fp16 (rows 0 and P+1 zero) ----------------
__global__ __launch_bounds__(256) void cvt_pad_k(const float* __restrict__ src, u16* __restrict__ dst,
    int P, int C){
  int n = NB*(P+2)*C;
  for(int i = blockIdx.x*256 + threadIdx.x; i < n; i += gridDim.x*256) cvtp(src, dst, P, C, i);
}
// ---------------- zero pad rows (0 and P+1) ----------------
__global__ __launch_bounds__(256) void zpad_k(u16* __restrict__ buf, int P){
  int n = NB*2*256;
  for(int i = blockIdx.x*256 + threadIdx.x; i < n; i += gridDim.x*256) zpr(buf, P, i);
}

// ---------------- conv1d via MFMA fp16 ----------------
template<int CIN, int KW, bool RELU, bool OBF>
__global__ __launch_bounds__(256) void mfconv_k(const u16* __restrict__ inb,
    const u16* __restrict__ wp, const float* __restrict__ bias, void* __restrict__ outp, int P){
  __shared__ __align__(16) u16 Al[4*66*8];            // 4224 B
  __shared__ __align__(16) u16 Bl[KW*4*256*8];        // KW3: 49152 B, KW1: 16384 B
  const int b = blockIdx.y;
  const int m0 = blockIdx.x * 64;
  const int tid = threadIdx.x;
  const int lane = tid & 63, wv = tid >> 6;
  const int lo16 = lane & 15, hi = lane >> 4;
  constexpr int K1 = (KW==1)? 1 : 0;
  const u16* inB = inb + (size_t)b*(P+2)*CIN;
  f32x4 acc[4][4];
#pragma unroll
  for(int i=0;i<4;i++)
#pragma unroll
    for(int j=0;j<4;j++) acc[i][j] = (f32x4){0.f,0.f,0.f,0.f};

  for(int c0=0; c0<CIN; c0+=32){
    __syncthreads();
    for(int idx = tid; idx < 264; idx += 256){
      int r = idx >> 2, q = idx & 3;
      int rowp = m0 + r;
      f16x8 v = (f16x8){0,0,0,0,0,0,0,0};
      if(rowp <= P+1) v = *(const f16x8*)&inB[(size_t)rowp*CIN + c0 + q*8];
      *(f16x8*)&Al[(q*66 + r)*8] = v;
    }
#pragma unroll
    for(int k=0;k<KW;k++){
      const u16* wr = &wp[((size_t)(k*256) + tid)*CIN + c0];
      f16x8 w0 = *(const f16x8*)&wr[0];
      f16x8 w1 = *(const f16x8*)&wr[8];
      f16x8 w2 = *(const f16x8*)&wr[16];
      f16x8 w3 = *(const f16x8*)&wr[24];
      *(f16x8*)&Bl[((k*4+0)*256 + tid)*8] = w0;
      *(f16x8*)&Bl[((k*4+1)*256 + tid)*8] = w1;
      *(f16x8*)&Bl[((k*4+2)*256 + tid)*8] = w2;
      *(f16x8*)&Bl[((k*4+3)*256 + tid)*8] = w3;
    }
    __syncthreads();
#pragma unroll
    for(int k=0;k<KW;k++){
      f16x8 af[4];
#pragma unroll
      for(int rf=0;rf<4;rf++)
        af[rf] = *(const f16x8*)&Al[(hi*66 + rf*16 + lo16 + k + K1)*8];
#pragma unroll
      for(int cf=0;cf<4;cf++){
        int o = wv*64 + cf*16 + lo16;
        f16x8 bf = *(const f16x8*)&Bl[((k*4+hi)*256 + o)*8];
#pragma unroll
        for(int rf=0;rf<4;rf++)
          acc[rf][cf] = __builtin_amdgcn_mfma_f32_16x16x32_f16(af[rf], bf, acc[rf][cf], 0, 0, 0);
      }
    }
  }
#pragma unroll
  for(int cf=0;cf<4;cf++){
    int o = wv*64 + cf*16 + lo16;
    float bs = bias[o];
#pragma unroll
    for(int rf=0;rf<4;rf++){
#pragma unroll
      for(int j=0;j<4;j++){
        int p = m0 + rf*16 + hi*4 + j;
        if(p < P){
          float v = acc[rf][cf][j] + bs;
          if(RELU) v = fmaxf(v, 0.f);
          if(OBF) ((u16*)outp)[((size_t)b*(P+2) + p + 1)*256 + o] = f2h(v);
          else    ((float*)outp)[((size_t)b*P + p)*256 + o] = v;
        }
      }
    }
  }
}

// ---------------- row squared norms (f1 and tenc merged) ----------------
__global__ __launch_bounds__(256) void norm2b_k(const float* __restrict__ x1, const float* __restrict__ x2,
    float* __restrict__ o1, float* __restrict__ o2){
  int r = blockIdx.x*4 + (threadIdx.x>>6);
  int lane = threadIdx.x & 63;
  const float* src; float* dst; int rr;
  if(r < NB*TF){ src = x1; dst = o1; rr = r; }
  else { rr = r - NB*TF; if(rr >= NB*TT) return; src = x2; dst = o2; }
  float4 v = ((const float4*)(src + (size_t)rr*256))[lane];
  float s = v.x*v.x + v.y*v.y + v.z*v.z + v.w*v.w;
  s = wsum(s);
  if(lane==0) dst[rr] = s;
}

// ---------------- score = -sqrt(max(||f||^2+||t||^2-2 f.t, 1e-12)) ----------------
__global__ __launch_bounds__(256) void score_gemm(const float* __restrict__ F, const float* __restrict__ Tn,
    const float* __restrict__ fn2, const float* __restrict__ tn2, float* __restrict__ outp){
  constexpr int KC = 32;
  __shared__ __align__(16) float As[KC][68];
  __shared__ __align__(16) float Bs[KC][68];
  const int b = blockIdx.z;
  const int t0 = blockIdx.y*64, s0 = blockIdx.x*64;
  const int tid = threadIdx.x, tx = tid&15, ty = tid>>4;
  const float* Fb = F  + (size_t)b*TF*256;
  const float* Tb = Tn + (size_t)b*TT*256;
  float acc[4][4] = {};
  const int lk = tid & 31, lt0 = (tid>>5)*8;
  for(int k0=0;k0<256;k0+=KC){
    __syncthreads();
#pragma unroll
    for(int i=0;i<8;i++){
      int t = t0 + lt0 + i;
      As[lk][lt0+i] = (t<TF)? Fb[(size_t)t*256 + k0 + lk] : 0.f;
      int s = s0 + lt0 + i;
      Bs[lk][lt0+i] = (s<TT)? Tb[(size_t)s*256 + k0 + lk] : 0.f;
    }
    __syncthreads();
#pragma unroll
    for(int k=0;k<KC;k++){
      float a0[4], b0[4];
      *(float4*)a0 = *(const float4*)&As[k][ty*4];
      *(float4*)b0 = *(const float4*)&Bs[k][tx*4];
#pragma unroll
      for(int i=0;i<4;i++)
#pragma unroll
        for(int j=0;j<4;j++) acc[i][j] = fmaf(a0[i], b0[j], acc[i][j]);
    }
  }
#pragma unroll
  for(int i=0;i<4;i++){
    int t = t0 + ty*4 + i;
    if(t<TF){
      float fn = fn2[b*TF + t];
#pragma unroll
      for(int j=0;j<4;j++){
        int s = s0 + tx*4 + j;
        if(s<TT){
          float d2 = fn + tn2[b*TT + s] - 2.f*acc[i][j];
          outp[((size_t)b*TF + t)*TT + s] = -sqrtf(fmaxf(d2, 1e-12f));
        }
      }
    }
  }
}

// ---------------- per-row log_softmax + prior, and Z2 = logsumexp([BLANK, row]) ----------------
__global__ __launch_bounds__(128) void softmax_prior_k(float* __restrict__ logp,
    const double* __restrict__ rowA, const double* __restrict__ colA, const double* __restrict__ sA,
    float* __restrict__ Z2){
  const int row = blockIdx.x;           // b*TF + t0
  const int t0 = row % TF;
  float* rp = logp + (size_t)row*TT;
  const int tid = threadIdx.x;
  __shared__ float sh2[2];
  float v[4]; int ix[4];
#pragma unroll
  for(int i=0;i<4;i++){ ix[i] = tid + i*128; v[i] = (ix[i]<TT)? rp[ix[i]] : BIGN; }
  float m = fmaxf(fmaxf(v[0],v[1]),fmaxf(v[2],v[3]));
#pragma unroll
  for(int o=32;o;o>>=1) m = fmaxf(m, __shfl_xor(m,o,64));
  if((tid&63)==0) sh2[tid>>6] = m;
  __syncthreads();
  m = fmaxf(sh2[0], sh2[1]);
  float s = 0.f;
#pragma unroll
  for(int i=0;i<4;i++) if(ix[i]<TT) s += __expf(v[i]-m);
  s = wsum(s);
  __syncthreads();
  if((tid&63)==0) sh2[tid>>6] = s;
  __syncthreads();
  s = sh2[0] + sh2[1];
  const float lse = m + __logf(s);
  const double rA = rowA[t0];
  float f[4]; float m2 = BIGN;
#pragma unroll
  for(int i=0;i<4;i++){
    if(ix[i]<TT){
      float pr = (float)(colA[ix[i]] + sA[t0+ix[i]] + rA);
      f[i] = (v[i]-lse) + pr;
      rp[ix[i]] = f[i];
      m2 = fmaxf(m2, f[i]);
    } else f[i] = BIGN;
  }
#pragma unroll
  for(int o=32;o;o>>=1) m2 = fmaxf(m2, __shfl_xor(m2,o,64));
  __syncthreads();
  if((tid&63)==0) sh2[tid>>6] = m2;
  __syncthreads();
  m2 = fmaxf(fmaxf(sh2[0],sh2[1]), -1.0f);
  float s2 = (tid==0)? __expf(-1.0f - m2) : 0.f;
#pragma unroll
  for(int i=0;i<4;i++) if(ix[i]<TT) s2 += __expf(f[i]-m2);
  s2 = wsum(s2);
  __syncthreads();
  if((tid&63)==0) sh2[tid>>6] = s2;
  __syncthreads();
  if(tid==0) Z2[row] = m2 + __logf(sh2[0]+sh2[1]);
}

// ---------------- scans ----------------
// R20 resolved the bottleneck: per-step DEPENDENCY-CHAIN latency (pairwise step = 2 nested
// lse2b ~600cyc), not issue or barriers. Fix: lse3b step -- ALL states computed from old
// values in parallel, chain depth 1 lse (~300cyc). Trans/wave rises 8->10; 2 waves/SIMD
// (R20 structure) covers the issue. Structure otherwise identical to R20 (passed, 16.0).
#define LCTC4(E) { \
  float n1 = shup1(a[3]); \
  float t1 = lse3b(a[1], a[0], n1)   + (E)[0]; \
  float t3 = lse3b(a[3], a[2], a[1]) + (E)[1]; \
  float t0 = lse2b(a[0], n1)   + EBL; \
  float t2 = lse2b(a[2], a[1]) + EBL; \
  a[0]=t0; a[1]=t1; a[2]=t2; a[3]=t3; }

#define CPREF2(E, K) { int kk=(K); if(kk>999) kk=999; int row = dir? (TF-1-kk) : kk; \
  const float* rpp = lp + (size_t)row*TT; \
  (E)[0]=rpp[jc0]*IL2; (E)[1]=rpp[jc1]*IL2; }

#define SEAMW(BUF) if(q<3 && lane>=wl0 && lane<wl0+4){ \
  float* sp = &sb[dir][q][BUF][(lane-wl0)*4]; \
  sp[0]=a[0]; sp[1]=a[1]; sp[2]=a[2]; sp[3]=a[3]; }

#define HALOR(BUF) if(q>0 && lane<4){ \
  const float* sp = &sb[dir][q-1][BUF][lane*4]; \
  a[0]=sp[0]; a[1]=sp[1]; a[2]=sp[2]; a[3]=sp[3]; }

#define MAS_STEP(E, TIDX) { \
  float n1 = shup1(q[6]); \
  u32 byte = 0; \
  if(lane>0 && n1 >= q[0]) byte |= 1u; \
  if(q[0] >= q[1]) byte |= 2u; \
  if(q[1] >= q[2]) byte |= 4u; \
  if(q[2] >= q[3]) byte |= 8u; \
  if(q[3] >= q[4]) byte |= 16u; \
  if(q[4] >= q[5]) byte |= 32u; \
  if(q[5] >= q[6]) byte |= 64u; \
  cb[(size_t)((TIDX)-1)*64 + lane] = (unsigned char)byte; \
  q[6] = fmaxf(q[6], q[5]) + (E)[6]; \
  q[5] = fmaxf(q[5], q[4]) + (E)[5]; \
  q[4] = fmaxf(q[4], q[3]) + (E)[4]; \
  q[3] = fmaxf(q[3], q[2]) + (E)[3]; \
  q[2] = fmaxf(q[2], q[1]) + (E)[2]; \
  q[1] = fmaxf(q[1], q[0]) + (E)[1]; \
  q[0] = fmaxf(q[0], n1) + (E)[0]; }

#define MPREF(E, ROW) { int rr=(ROW); rr = (rr>TF-1)? (TF-1) : rr; const float* rpp = lp + (size_t)rr*TT; \
  (E)[0]=rpp[jc[0]]; (E)[1]=rpp[jc[1]]; (E)[2]=rpp[jc[2]]; (E)[3]=rpp[jc[3]]; \
  (E)[4]=rpp[jc[4]]; (E)[5]=rpp[jc[5]]; (E)[6]=rpp[jc[6]]; }

__global__ __launch_bounds__(512) __attribute__((amdgpu_waves_per_eu(2,2)))
void scan_k(const float* __restrict__ logp,
    const float* __restrict__ Z2, unsigned char* __restrict__ cmpb, float* __restrict__ nll){
  const int lane = threadIdx.x & 63;
  const int wave = threadIdx.x >> 6;
  constexpr float IL2 = 1.4426950408889634f;
  constexpr float L2  = 0.6931471805599453f;
  if(blockIdx.x < NB){
    const int b = blockIdx.x;
    const float* lp = logp + (size_t)b*TF*TT;
    __shared__ float af[801], ag[801];
    __shared__ float sb[2][3][2][16];    // [dir][seam][buf][16]
    const int dir = wave >> 2;           // 0: t=0..999 ; 1: t=1999..1000 (state w=800-s)
    const int q   = wave & 3;            // quarter
    const int sbase = (q==0)? 0 : 200*q - 16;
    const int olo = 200*q;
    const int ohi = (q<3)? 200*q+199 : 800;
    const int wl0 = (q==0)? 46 : 50;     // lanes holding the top-16 owned states
    double zs = 0.0;
    if(wave==0){
      for(int t=lane; t<TF; t+=64) zs += (double)Z2[b*TF + t];
#pragma unroll
      for(int o=32;o;o>>=1) zs += __shfl_xor(zs, o, 64);
    }
    // emission cols for odd states s0+1 (i=1) and s0+3 (i=3): j = sbase/2 + 2*lane (+1)
    int j0 = sbase/2 + 2*lane, j1 = j0 + 1;
    if(dir){ j0 = TT-1-j0; j1 = TT-1-j1; }
    const int jc0 = (j0<0)? 0 : ((j0>TT-1)? TT-1 : j0);
    const int jc1 = (j1<0)? 0 : ((j1>TT-1)? TT-1 : j1);
    float a[4];
#pragma unroll
    for(int i=0;i<4;i++) a[i] = BIGN;
    if(q==0 && lane==0){
      a[0] = -1.0f*IL2;
      a[1] = (dir? lp[(size_t)(TF-1)*TT + (TT-1)] : lp[0]) * IL2;
    }
    const float EBL = -1.0f*IL2;
    SEAMW(0);                            // initial seam (step-0 state)
    float e0[2],e1[2],e2[2],e3[2],e4[2],e5[2],e6[2],e7[2];
    CPREF2(e0,1); CPREF2(e1,2); CPREF2(e2,3); CPREF2(e3,4);
    CPREF2(e4,5); CPREF2(e5,6); CPREF2(e6,7); CPREF2(e7,8);
    __syncthreads();
    int k = 1, kb = 0;
    for(; k + 8 <= 1000; k += 8, kb++){
      HALOR(kb&1);
      LCTC4(e0); CPREF2(e0, k+8);
      LCTC4(e1); CPREF2(e1, k+9);
      LCTC4(e2); CPREF2(e2, k+10);
      LCTC4(e3); CPREF2(e3, k+11);
      LCTC4(e4); CPREF2(e4, k+12);
      LCTC4(e5); CPREF2(e5, k+13);
      LCTC4(e6); CPREF2(e6, k+14);
      LCTC4(e7); CPREF2(e7, k+15);
      SEAMW((kb+1)&1);
      __syncthreads();
    }
    // tail (<=7 steps; halo 16 >= 2*7 front)
    HALOR(kb&1);
    for(; k<=999; k++){
      float P[2];
      CPREF2(P, k);
      LCTC4(P);
    }
    float* dst = dir? ag : af;
#pragma unroll
    for(int i=0;i<4;i++){
      int s = sbase + 4*lane + i;
      if(s>=olo && s<=ohi) dst[s] = a[i];
    }
    __syncthreads();
    if(wave==0){
      float acc = BIGN;
      for(int s = lane; s <= 800; s += 64){
        float x0 = af[s];
        float x1 = (s>=1)? af[s-1] : BIGN;
        float x2 = ((s&1) && s>=3)? af[s-2] : BIGN;
        float A1 = lse3b(x0,x1,x2);                 // one transition, no emission
        acc = lse2b(acc, A1 + ag[800-s]);
      }
#pragma unroll
      for(int o=32;o;o>>=1) acc = lse2b(acc, __shfl_xor(acc,o,64));
      if(lane==0) nll[b] = -((acc*L2) - (float)zs);
    }
  } else {
    if(wave) return;
    const int b = blockIdx.x - NB;
    const float* lp = logp + (size_t)b*TF*TT;
    unsigned char* cb = cmpb + (size_t)b*TF*64;
    int jc[7];
#pragma unroll
    for(int i=0;i<7;i++){ int j = 7*lane + i; jc[i] = (j < TT)? j : (TT-1); }
    float q[7];
#pragma unroll
    for(int i=0;i<7;i++) q[i] = BIGN;
    if(lane==0) q[0] = lp[0];
    float e0[7],e1[7],e2[7],e3[7];
    MPREF(e0,1); MPREF(e1,2); MPREF(e2,3); MPREF(e3,4);
    int t0 = 1;
    for(; t0 + 4 <= TF; t0 += 4){
      MAS_STEP(e0, t0);   MPREF(e0, t0+4);
      MAS_STEP(e1, t0+1); MPREF(e1, t0+5);
      MAS_STEP(e2, t0+2); MPREF(e2, t0+6);
      MAS_STEP(e3, t0+3); MPREF(e3, t0+7);
    }
    for(; t0<TF; t0++){
      float P[7];
      MPREF(P, t0);
      MAS_STEP(P, t0);
    }
    {
      float n1 = shup1(q[6]);
      u32 byte = 0;
      if(lane>0 && n1 >= q[0]) byte |= 1u;
      if(q[0] >= q[1]) byte |= 2u;
      if(q[1] >= q[2]) byte |= 4u;
      if(q[2] >= q[3]) byte |= 8u;
      if(q[3] >= q[4]) byte |= 16u;
      if(q[4] >= q[5]) byte |= 32u;
      if(q[5] >= q[6]) byte |= 64u;
      cb[(size_t)(TF-1)*64 + lane] = (unsigned char)byte;
    }
  }
}

// ---------------- MAS backtrack + ds + gather ----------------
__global__ __launch_bounds__(256) void masback_k(const unsigned char* __restrict__ cmpb,
    const float* __restrict__ logp, float* __restrict__ ds, float* __restrict__ gsum){
  const int b = blockIdx.x;
  const unsigned char* cb = cmpb + (size_t)b*TF*64;
  __shared__ unsigned char bits[500*64];
  __shared__ short Ash[TF];
  __shared__ int cnt[TT];
  __shared__ float ps[4];
  int a = TT-1;
  for(int ch=3; ch>=0; ch--){
    const int tlo = ch*500;
    __syncthreads();
    for(int i=threadIdx.x;i<8000;i+=256) ((u32*)bits)[i] = ((const u32*)(cb + (size_t)tlo*64))[i];
    __syncthreads();
    if(threadIdx.x==0){
      int thi = tlo + 499;
      if(ch==3){ Ash[TF-1] = (short)(TT-1); thi = TF-2; }
      for(int t=thi;t>=tlo;t--){
        if(a > 0){
          unsigned char w = bits[(t-tlo)*64 + a/7];
          a -= (int)((w >> (a%7)) & 1u);
        }
        Ash[t] = (short)a;
      }
    }
  }
  __syncthreads();
  for(int i=threadIdx.x;i<TT;i+=256) cnt[i]=0;
  __syncthreads();
  float part = 0.f;
  const float* lp = logp + (size_t)b*TF*TT;
  for(int t=threadIdx.x;t<TF;t+=256){
    int at = Ash[t];
    atomicAdd(&cnt[at], 1);
    part += lp[(size_t)t*TT + at];
  }
  __syncthreads();
  for(int i=threadIdx.x;i<TT;i+=256) ds[(size_t)b*TT + i] = (float)cnt[i];
  part = wsum(part);
  if((threadIdx.x&63)==0) ps[threadIdx.x>>6] = part;
  __syncthreads();
  if(threadIdx.x==0) gsum[b] = ps[0]+ps[1]+ps[2]+ps[3];
}

__global__ void final_k(const float* __restrict__ nll, const float* __restrict__ gsum, float* __restrict__ out){
  if(threadIdx.x==0 && blockIdx.x==0){
    float fs=0.f, bs=0.f;
    for(int b=0;b<NB;b++){ fs += nll[b] / (float)TT; bs += gsum[b] / (float)TF; }
    out[6400] = -(bs / (float)NB);   // bin_loss
    out[6401] = fs / (float)NB;      // forwardsum_loss
  }
}

extern "C" void kernel_launch(void* const* d_in, const int* in_sizes, int n_in,
                              void* d_out, int out_size, void* d_ws, size_t ws_size,
                              hipStream_t stream){
  const float* speech = (const float*)d_in[0];
  const float* txt    = (const float*)d_in[1];
  const float* tw1 = (const float*)d_in[4];
  const float* tb1 = (const float*)d_in[5];
  const float* tw2 = (const float*)d_in[6];
  const float* tb2 = (const float*)d_in[7];
  const float* fw1 = (const float*)d_in[8];
  const float* fb1 = (const float*)d_in[9];
  const float* fw2 = (const float*)d_in[10];
  const float* fb2 = (const float*)d_in[11];
  const float* fw3 = (const float*)d_in[12];
  const float* fb3 = (const float*)d_in[13];
  float* out  = (float*)d_out;
  float* ds   = out;                 // (16,400)
  float* logp = out + 6402;          // (16,2000,400) -- also conv scratch until score_gemm
  char* ws = (char*)d_ws;
  double* lgt  = (double*)(ws + 0);
  double* rowA = (double*)(ws + 20480);
  double* colA = (double*)(ws + 36864);
  double* sA   = (double*)(ws + 40960);
  float*  nll  = (float*)(ws + 61440);
  float*  gsum = (float*)(ws + 61696);
  float*  Z2   = (float*)(ws + 65536);
  float*  fn2  = (float*)(ws + 196608);
  float*  tn2  = (float*)(ws + 327680);
  unsigned char* cmpb = (unsigned char*)(ws + 360448);
  float*  tenc = (float*)(ws + 2408448);
  float*  f1   = (float*)(ws + 8962048);   // f_enc fp32 (16,2000,256)
  if(ws_size < 41730048) return;

  // conv scratch inside the (dead until score_gemm) logp region; 256B-aligned base
  char* lr = (char*)(((uintptr_t)logp + 255) & ~(uintptr_t)255);
  u16* inbfT = (u16*)lr;                    // (16,402,256)  3.29MB   [txt phase]
  u16* tout1 = (u16*)(lr + 4000000);        // (16,402,256)  3.29MB   [txt phase]
  u16* inbfA = (u16*)lr;                    // (16,2002,512) 32.80MB  [f phase 1; AFTER txt phase]
  u16* out2  = (u16*)lr;                    // (16,2002,256) 16.40MB  [f phase 3, after inbfA dead]
  u16* wbase = (u16*)(lr + 32900000);       // packs, 1.84MB, live all conv phases
  u16* fw1p = wbase;
  u16* fw2p = wbase + 393216;
  u16* fw3p = wbase + 589824;
  u16* tw1p = wbase + 655360;
  u16* tw2p = wbase + 851968;
  u16* out1  = (u16*)(lr + 34750000);       // (16,2002,256) 16.40MB

  k_lgt  <<<10,256,0,stream>>>(lgt);
  k_terms<<<10,256,0,stream>>>(lgt,rowA,colA,sA);

  prep1_k<<<2048,256,0,stream>>>(fw1,fw2,fw3,tw1,tw2, txt,
                                 fw1p,fw2p,fw3p,tw1p,tw2p, inbfT, tout1, out1);

  // txt path
  mfconv_k<256,3,true ,true ><<<dim3(7,NB),256,0,stream>>>(inbfT, tw1p, tb1, tout1, TT);
  mfconv_k<256,1,false,false><<<dim3(7,NB),256,0,stream>>>(tout1, tw2p, tb2, tenc, TT);

  // f path (speech convert must run AFTER txt phase: inbfA overlaps inbfT/tout1)
  cvt_pad_k<<<4096,256,0,stream>>>(speech, inbfA, TF, 512);
  mfconv_k<512,3,true ,true ><<<dim3(32,NB),256,0,stream>>>(inbfA, fw1p, fb1, out1, TF);
  zpad_k<<<32,256,0,stream>>>(out2, TF);               // after fconv1: inbfA region dead
  mfconv_k<256,3,true ,true ><<<dim3(32,NB),256,0,stream>>>(out1, fw2p, fb2, out2, TF);
  mfconv_k<256,1,false,false><<<dim3(32,NB),256,0,stream>>>(out2, fw3p, fb3, f1, TF);

  norm2b_k<<<(NB*TF+NB*TT)/4,256,0,stream>>>(f1, tenc, fn2, tn2);

  score_gemm<<<dim3(7,32,NB),256,0,stream>>>(f1, tenc, fn2, tn2, logp);
  softmax_prior_k<<<NB*TF,128,0,stream>>>(logp, rowA, colA, sA, Z2);

  scan_k<<<2*NB,512,0,stream>>>(logp, Z2, cmpb, nll);
  masback_k<<<NB,256,0,stream>>>(cmpb, logp, ds, gsum);
  final_k<<<1,64,0,stream>>>(nll, gsum, out);
}

// Round 22
// 730.013 us; speedup vs baseline: 1.1211x; 1.1211x over previous
//
#include <hip/hip_runtime.h>
#include <math.h>

typedef unsigned int u32;
typedef unsigned long long u64;
typedef unsigned short u16;
typedef __attribute__((ext_vector_type(8))) _Float16 f16x8;  // 8 fp16 (4 VGPR)
typedef __attribute__((ext_vector_type(4))) _Float16 f16x4;
typedef __attribute__((ext_vector_type(4))) float f32x4;

#define BIGN (-1e30f)

static constexpr int NB = 16;     // batch
static constexpr int TF = 2000;   // T_FEATS
static constexpr int TT = 400;    // T_TEXT

__device__ __forceinline__ float wsum(float v){
#pragma unroll
  for(int o=32;o;o>>=1) v += __shfl_xor(v,o,64);
  return v;
}
__device__ __forceinline__ float EXP2(float x){ return __builtin_amdgcn_exp2f(x); }
__device__ __forceinline__ float LOG2(float x){ return __builtin_amdgcn_logf(x); }
__device__ __forceinline__ float lse2b(float x, float y){
  float m = fmaxf(x,y);
  return m + LOG2(1.0f + EXP2(-fabsf(x-y)));
}
__device__ __forceinline__ float lse3b(float x, float y, float z){
  float mx = fmaxf(fmaxf(x,y),z);
  float md = __builtin_amdgcn_fmed3f(x,y,z);
  float mn = fminf(fminf(x,y),z);
  return mx + LOG2(1.0f + EXP2(md-mx) + EXP2(mn-mx));
}
__device__ __forceinline__ u16 f2h(float v){
  _Float16 h = (_Float16)v;              // round-nearest-even
  return *(u16*)&h;
}
// lane i <- lane i-1, lane 0 <- BIGN. DPP wave_shr1 (0x138): pure VALU, no LDS/lgkmcnt.
__device__ __forceinline__ float shup1(float v){
  int r = __builtin_amdgcn_update_dpp(__float_as_int(BIGN), __float_as_int(v),
                                      0x138, 0xf, 0xf, false);
  return __int_as_float(r);
}

// ---------------- gammaln tables ----------------
__global__ void k_lgt(double* lgt){
  int m = blockIdx.x*blockDim.x + threadIdx.x;
  if(m < 2432) lgt[m] = (m>=1)? lgamma((double)m) : 0.0;
}
__global__ void k_terms(const double* __restrict__ lgt, double* rowA, double* colA, double* sA){
  int i = blockIdx.x*blockDim.x + threadIdx.x;
  if(i < TF)   rowA[i] = -lgt[2401] - lgt[i+1] - lgt[2000-i] + lgt[2001];
  if(i < TT)   colA[i] =  lgt[401]  - lgt[i+2] - lgt[400-i];
  if(i < 2399) sA[i]   =  lgt[i+2]  + lgt[2399-i];
}

// ---------------- consolidated prep: 5 weight packs + txt cvt + zpad(tout1,out1) ----------------
__device__ __forceinline__ void packf(const float* __restrict__ w, u16* __restrict__ dst,
    int CIN, int KW, int i){
  int k = i % KW;
  int c = (i / KW) % CIN;
  int o = i / (KW*CIN);
  dst[((size_t)k*256 + o)*CIN + c] = f2h(w[i]);
}
__device__ __forceinline__ void cvtp(const float* __restrict__ src, u16* __restrict__ dst,
    int P, int C, int i){
  int c = i % C;
  int p = (i / C) % (P+2);
  int b = i / (C*(P+2));
  float v = 0.f;
  if(p>=1 && p<=P) v = src[((size_t)b*P + (p-1))*C + c];
  dst[i] = f2h(v);
}
__device__ __forceinline__ void zpr(u16* __restrict__ buf, int P, int j){
  int c = j % 256;
  int s = (j / 256) & 1;
  int b = j / 512;
  buf[((size_t)b*(P+2) + (s? P+1 : 0))*256 + c] = 0;
}
__global__ __launch_bounds__(256) void prep1_k(
    const float* __restrict__ fw1, const float* __restrict__ fw2, const float* __restrict__ fw3,
    const float* __restrict__ tw1, const float* __restrict__ tw2, const float* __restrict__ txt,
    u16* fw1p, u16* fw2p, u16* fw3p, u16* tw1p, u16* tw2p,
    u16* inbfT, u16* tout1, u16* out1){
  constexpr int N = 393216+196608+65536+196608+65536+1646592+8192+8192;
  for(int i = blockIdx.x*256 + threadIdx.x; i < N; i += gridDim.x*256){
    int j = i;
    if(j < 393216){ packf(fw1, fw1p, 512, 3, j); continue; } j -= 393216;
    if(j < 196608){ packf(fw2, fw2p, 256, 3, j); continue; } j -= 196608;
    if(j < 65536) { packf(fw3, fw3p, 256, 1, j); continue; } j -= 65536;
    if(j < 196608){ packf(tw1, tw1p, 256, 3, j); continue; } j -= 196608;
    if(j < 65536) { packf(tw2, tw2p, 256, 1, j); continue; } j -= 65536;
    if(j < 1646592){ cvtp(txt, inbfT, TT, 256, j); continue; } j -= 1646592;
    if(j < 8192) { zpr(tout1, TT, j); continue; } j -= 8192;
    zpr(out1, TF, j);
  }
}

// ---------------- fp32 -> padded fp16 (rows 0 and P+1 zero) ----------------
__global__ __launch_bounds__(256) void cvt_pad_k(const float* __restrict__ src, u16* __restrict__ dst,
    int P, int C){
  int n = NB*(P+2)*C;
  for(int i = blockIdx.x*256 + threadIdx.x; i < n; i += gridDim.x*256) cvtp(src, dst, P, C, i);
}
// ---------------- zero pad rows (0 and P+1) ----------------
__global__ __launch_bounds__(256) void zpad_k(u16* __restrict__ buf, int P){
  int n = NB*2*256;
  for(int i = blockIdx.x*256 + threadIdx.x; i < n; i += gridDim.x*256) zpr(buf, P, i);
}

// ---------------- conv1d via MFMA fp16 ----------------
// OM: 0 = fp32 plain (B,P,256), 1 = fp16 padded (B,P+2,256), 2 = fp16 plain (B,P,256)
template<int CIN, int KW, bool RELU, int OM>
__global__ __launch_bounds__(256) void mfconv_k(const u16* __restrict__ inb,
    const u16* __restrict__ wp, const float* __restrict__ bias, void* __restrict__ outp, int P){
  __shared__ __align__(16) u16 Al[4*66*8];            // 4224 B
  __shared__ __align__(16) u16 Bl[KW*4*256*8];        // KW3: 49152 B, KW1: 16384 B
  const int b = blockIdx.y;
  const int m0 = blockIdx.x * 64;
  const int tid = threadIdx.x;
  const int lane = tid & 63, wv = tid >> 6;
  const int lo16 = lane & 15, hi = lane >> 4;
  constexpr int K1 = (KW==1)? 1 : 0;
  const u16* inB = inb + (size_t)b*(P+2)*CIN;
  f32x4 acc[4][4];
#pragma unroll
  for(int i=0;i<4;i++)
#pragma unroll
    for(int j=0;j<4;j++) acc[i][j] = (f32x4){0.f,0.f,0.f,0.f};

  for(int c0=0; c0<CIN; c0+=32){
    __syncthreads();
    for(int idx = tid; idx < 264; idx += 256){
      int r = idx >> 2, q = idx & 3;
      int rowp = m0 + r;
      f16x8 v = (f16x8){0,0,0,0,0,0,0,0};
      if(rowp <= P+1) v = *(const f16x8*)&inB[(size_t)rowp*CIN + c0 + q*8];
      *(f16x8*)&Al[(q*66 + r)*8] = v;
    }
#pragma unroll
    for(int k=0;k<KW;k++){
      const u16* wr = &wp[((size_t)(k*256) + tid)*CIN + c0];
      f16x8 w0 = *(const f16x8*)&wr[0];
      f16x8 w1 = *(const f16x8*)&wr[8];
      f16x8 w2 = *(const f16x8*)&wr[16];
      f16x8 w3 = *(const f16x8*)&wr[24];
      *(f16x8*)&Bl[((k*4+0)*256 + tid)*8] = w0;
      *(f16x8*)&Bl[((k*4+1)*256 + tid)*8] = w1;
      *(f16x8*)&Bl[((k*4+2)*256 + tid)*8] = w2;
      *(f16x8*)&Bl[((k*4+3)*256 + tid)*8] = w3;
    }
    __syncthreads();
#pragma unroll
    for(int k=0;k<KW;k++){
      f16x8 af[4];
#pragma unroll
      for(int rf=0;rf<4;rf++)
        af[rf] = *(const f16x8*)&Al[(hi*66 + rf*16 + lo16 + k + K1)*8];
#pragma unroll
      for(int cf=0;cf<4;cf++){
        int o = wv*64 + cf*16 + lo16;
        f16x8 bf = *(const f16x8*)&Bl[((k*4+hi)*256 + o)*8];
#pragma unroll
        for(int rf=0;rf<4;rf++)
          acc[rf][cf] = __builtin_amdgcn_mfma_f32_16x16x32_f16(af[rf], bf, acc[rf][cf], 0, 0, 0);
      }
    }
  }
#pragma unroll
  for(int cf=0;cf<4;cf++){
    int o = wv*64 + cf*16 + lo16;
    float bs = bias[o];
#pragma unroll
    for(int rf=0;rf<4;rf++){
#pragma unroll
      for(int j=0;j<4;j++){
        int p = m0 + rf*16 + hi*4 + j;
        if(p < P){
          float v = acc[rf][cf][j] + bs;
          if(RELU) v = fmaxf(v, 0.f);
          if(OM==1)      ((u16*)outp)[((size_t)b*(P+2) + p + 1)*256 + o] = f2h(v);
          else if(OM==2) ((u16*)outp)[((size_t)b*P + p)*256 + o] = f2h(v);
          else           ((float*)outp)[((size_t)b*P + p)*256 + o] = v;
        }
      }
    }
  }
}

// ---------------- row squared norms from fp16 encodings (f and t merged) ----------------
__global__ __launch_bounds__(256) void norm2h_k(const u16* __restrict__ fh, const u16* __restrict__ th,
    float* __restrict__ o1, float* __restrict__ o2){
  int r = blockIdx.x*4 + (threadIdx.x>>6);
  int lane = threadIdx.x & 63;
  const u16* src; float* dst; int rr;
  if(r < NB*TF){ src = fh; dst = o1; rr = r; }
  else { rr = r - NB*TF; if(rr >= NB*TT) return; src = th; dst = o2; }
  f16x4 v = *(const f16x4*)&src[(size_t)rr*256 + lane*4];
  float x0=(float)v[0], x1=(float)v[1], x2=(float)v[2], x3=(float)v[3];
  float s = x0*x0 + x1*x1 + x2*x2 + x3*x3;
  s = wsum(s);
  if(lane==0) dst[rr] = s;
}

// ---------------- score = -sqrt(max(||f||^2+||t||^2-2 f.t, 1e-12)) via MFMA fp16 ----------------
// Tile 64 f-rows x 64 t-rows, K=256 in chunks of 32. Fragment layout identical to mfconv
// (verified): A rows indexed by lo16, k-group by hi; D[row=hi*4+j][col=lo16].
__global__ __launch_bounds__(256) void score_mf(const u16* __restrict__ fh, const u16* __restrict__ th,
    const float* __restrict__ fn2, const float* __restrict__ tn2, float* __restrict__ outp){
  __shared__ __align__(16) u16 Fl[4*64*8];   // [kgroup][frow][8]
  __shared__ __align__(16) u16 Tl[4*64*8];   // [kgroup][trow][8]
  const int b = blockIdx.z;
  const int t0 = blockIdx.y*64;    // f rows
  const int s0 = blockIdx.x*64;    // t rows (output cols)
  const int tid = threadIdx.x;
  const int lane = tid & 63, wv = tid >> 6;
  const int lo16 = lane & 15, hi = lane >> 4;
  const u16* fB = fh + (size_t)b*TF*256;
  const u16* tB = th + (size_t)b*TT*256;
  f32x4 acc[4];
#pragma unroll
  for(int c=0;c<4;c++) acc[c] = (f32x4){0.f,0.f,0.f,0.f};
  const int srow = tid >> 2, sq = tid & 3;   // staging: 4 threads per row, coalesced 64B
  for(int k0=0;k0<256;k0+=32){
    __syncthreads();
    {
      f16x8 fv = (f16x8){0,0,0,0,0,0,0,0};
      int fr = t0 + srow;
      if(fr < TF) fv = *(const f16x8*)&fB[(size_t)fr*256 + k0 + sq*8];
      *(f16x8*)&Fl[(sq*64 + srow)*8] = fv;
      f16x8 tv = (f16x8){0,0,0,0,0,0,0,0};
      int tr = s0 + srow;
      if(tr < TT) tv = *(const f16x8*)&tB[(size_t)tr*256 + k0 + sq*8];
      *(f16x8*)&Tl[(sq*64 + srow)*8] = tv;
    }
    __syncthreads();
    f16x8 af = *(const f16x8*)&Fl[(hi*64 + wv*16 + lo16)*8];
#pragma unroll
    for(int cf=0;cf<4;cf++){
      f16x8 bf = *(const f16x8*)&Tl[(hi*64 + cf*16 + lo16)*8];
      acc[cf] = __builtin_amdgcn_mfma_f32_16x16x32_f16(af, bf, acc[cf], 0, 0, 0);
    }
  }
#pragma unroll
  for(int cf=0;cf<4;cf++){
    int s = s0 + cf*16 + lo16;
#pragma unroll
    for(int j=0;j<4;j++){
      int f = t0 + wv*16 + hi*4 + j;
      if(f < TF && s < TT){
        float d2 = fn2[b*TF + f] + tn2[b*TT + s] - 2.f*acc[cf][j];
        outp[((size_t)b*TF + f)*TT + s] = -sqrtf(fmaxf(d2, 1e-12f));
      }
    }
  }
}

// ---------------- per-row log_softmax + prior, and Z2 = logsumexp([BLANK, row]) ----------------
__global__ __launch_bounds__(128) void softmax_prior_k(float* __restrict__ logp,
    const double* __restrict__ rowA, const double* __restrict__ colA, const double* __restrict__ sA,
    float* __restrict__ Z2){
  const int row = blockIdx.x;           // b*TF + t0
  const int t0 = row % TF;
  float* rp = logp + (size_t)row*TT;
  const int tid = threadIdx.x;
  __shared__ float sh2[2];
  float v[4]; int ix[4];
#pragma unroll
  for(int i=0;i<4;i++){ ix[i] = tid + i*128; v[i] = (ix[i]<TT)? rp[ix[i]] : BIGN; }
  float m = fmaxf(fmaxf(v[0],v[1]),fmaxf(v[2],v[3]));
#pragma unroll
  for(int o=32;o;o>>=1) m = fmaxf(m, __shfl_xor(m,o,64));
  if((tid&63)==0) sh2[tid>>6] = m;
  __syncthreads();
  m = fmaxf(sh2[0], sh2[1]);
  float s = 0.f;
#pragma unroll
  for(int i=0;i<4;i++) if(ix[i]<TT) s += __expf(v[i]-m);
  s = wsum(s);
  __syncthreads();
  if((tid&63)==0) sh2[tid>>6] = s;
  __syncthreads();
  s = sh2[0] + sh2[1];
  const float lse = m + __logf(s);
  const double rA = rowA[t0];
  float f[4]; float m2 = BIGN;
#pragma unroll
  for(int i=0;i<4;i++){
    if(ix[i]<TT){
      float pr = (float)(colA[ix[i]] + sA[t0+ix[i]] + rA);
      f[i] = (v[i]-lse) + pr;
      rp[ix[i]] = f[i];
      m2 = fmaxf(m2, f[i]);
    } else f[i] = BIGN;
  }
#pragma unroll
  for(int o=32;o;o>>=1) m2 = fmaxf(m2, __shfl_xor(m2,o,64));
  __syncthreads();
  if((tid&63)==0) sh2[tid>>6] = m2;
  __syncthreads();
  m2 = fmaxf(fmaxf(sh2[0],sh2[1]), -1.0f);
  float s2 = (tid==0)? __expf(-1.0f - m2) : 0.f;
#pragma unroll
  for(int i=0;i<4;i++) if(ix[i]<TT) s2 += __expf(f[i]-m2);
  s2 = wsum(s2);
  __syncthreads();
  if((tid&63)==0) sh2[tid>>6] = s2;
  __syncthreads();
  if(tid==0) Z2[row] = m2 + __logf(sh2[0]+sh2[1]);
}

// ---------------- scans (R20/R21 plateau form: 261us, four falsified improvement theories) ----------------
#define LCTC4(E) { \
  float n1 = shup1(a[3]); \
  float t1 = lse3b(a[1], a[0], n1)   + (E)[0]; \
  float t3 = lse3b(a[3], a[2], a[1]) + (E)[1]; \
  float t0 = lse2b(a[0], n1)   + EBL; \
  float t2 = lse2b(a[2], a[1]) + EBL; \
  a[0]=t0; a[1]=t1; a[2]=t2; a[3]=t3; }

#define CPREF2(E, K) { int kk=(K); if(kk>999) kk=999; int row = dir? (TF-1-kk) : kk; \
  const float* rpp = lp + (size_t)row*TT; \
  (E)[0]=rpp[jc0]*IL2; (E)[1]=rpp[jc1]*IL2; }

#define SEAMW(BUF) if(q<3 && lane>=wl0 && lane<wl0+4){ \
  float* sp = &sb[dir][q][BUF][(lane-wl0)*4]; \
  sp[0]=a[0]; sp[1]=a[1]; sp[2]=a[2]; sp[3]=a[3]; }

#define HALOR(BUF) if(q>0 && lane<4){ \
  const float* sp = &sb[dir][q-1][BUF][lane*4]; \
  a[0]=sp[0]; a[1]=sp[1]; a[2]=sp[2]; a[3]=sp[3]; }

#define MAS_STEP(E, TIDX) { \
  float n1 = shup1(q[6]); \
  u32 byte = 0; \
  if(lane>0 && n1 >= q[0]) byte |= 1u; \
  if(q[0] >= q[1]) byte |= 2u; \
  if(q[1] >= q[2]) byte |= 4u; \
  if(q[2] >= q[3]) byte |= 8u; \
  if(q[3] >= q[4]) byte |= 16u; \
  if(q[4] >= q[5]) byte |= 32u; \
  if(q[5] >= q[6]) byte |= 64u; \
  cb[(size_t)((TIDX)-1)*64 + lane] = (unsigned char)byte; \
  q[6] = fmaxf(q[6], q[5]) + (E)[6]; \
  q[5] = fmaxf(q[5], q[4]) + (E)[5]; \
  q[4] = fmaxf(q[4], q[3]) + (E)[4]; \
  q[3] = fmaxf(q[3], q[2]) + (E)[3]; \
  q[2] = fmaxf(q[2], q[1]) + (E)[2]; \
  q[1] = fmaxf(q[1], q[0]) + (E)[1]; \
  q[0] = fmaxf(q[0], n1) + (E)[0]; }

#define MPREF(E, ROW) { int rr=(ROW); rr = (rr>TF-1)? (TF-1) : rr; const float* rpp = lp + (size_t)rr*TT; \
  (E)[0]=rpp[jc[0]]; (E)[1]=rpp[jc[1]]; (E)[2]=rpp[jc[2]]; (E)[3]=rpp[jc[3]]; \
  (E)[4]=rpp[jc[4]]; (E)[5]=rpp[jc[5]]; (E)[6]=rpp[jc[6]]; }

__global__ __launch_bounds__(512) __attribute__((amdgpu_waves_per_eu(2,2)))
void scan_k(const float* __restrict__ logp,
    const float* __restrict__ Z2, unsigned char* __restrict__ cmpb, float* __restrict__ nll){
  const int lane = threadIdx.x & 63;
  const int wave = threadIdx.x >> 6;
  constexpr float IL2 = 1.4426950408889634f;
  constexpr float L2  = 0.6931471805599453f;
  if(blockIdx.x < NB){
    const int b = blockIdx.x;
    const float* lp = logp + (size_t)b*TF*TT;
    __shared__ float af[801], ag[801];
    __shared__ float sb[2][3][2][16];    // [dir][seam][buf][16]
    const int dir = wave >> 2;
    const int q   = wave & 3;
    const int sbase = (q==0)? 0 : 200*q - 16;
    const int olo = 200*q;
    const int ohi = (q<3)? 200*q+199 : 800;
    const int wl0 = (q==0)? 46 : 50;
    double zs = 0.0;
    if(wave==0){
      for(int t=lane; t<TF; t+=64) zs += (double)Z2[b*TF + t];
#pragma unroll
      for(int o=32;o;o>>=1) zs += __shfl_xor(zs, o, 64);
    }
    int j0 = sbase/2 + 2*lane, j1 = j0 + 1;
    if(dir){ j0 = TT-1-j0; j1 = TT-1-j1; }
    const int jc0 = (j0<0)? 0 : ((j0>TT-1)? TT-1 : j0);
    const int jc1 = (j1<0)? 0 : ((j1>TT-1)? TT-1 : j1);
    float a[4];
#pragma unroll
    for(int i=0;i<4;i++) a[i] = BIGN;
    if(q==0 && lane==0){
      a[0] = -1.0f*IL2;
      a[1] = (dir? lp[(size_t)(TF-1)*TT + (TT-1)] : lp[0]) * IL2;
    }
    const float EBL = -1.0f*IL2;
    SEAMW(0);
    float e0[2],e1[2],e2[2],e3[2],e4[2],e5[2],e6[2],e7[2];
    CPREF2(e0,1); CPREF2(e1,2); CPREF2(e2,3); CPREF2(e3,4);
    CPREF2(e4,5); CPREF2(e5,6); CPREF2(e6,7); CPREF2(e7,8);
    __syncthreads();
    int k = 1, kb = 0;
    for(; k + 8 <= 1000; k += 8, kb++){
      HALOR(kb&1);
      LCTC4(e0); CPREF2(e0, k+8);
      LCTC4(e1); CPREF2(e1, k+9);
      LCTC4(e2); CPREF2(e2, k+10);
      LCTC4(e3); CPREF2(e3, k+11);
      LCTC4(e4); CPREF2(e4, k+12);
      LCTC4(e5); CPREF2(e5, k+13);
      LCTC4(e6); CPREF2(e6, k+14);
      LCTC4(e7); CPREF2(e7, k+15);
      SEAMW((kb+1)&1);
      __syncthreads();
    }
    HALOR(kb&1);
    for(; k<=999; k++){
      float P[2];
      CPREF2(P, k);
      LCTC4(P);
    }
    float* dst = dir? ag : af;
#pragma unroll
    for(int i=0;i<4;i++){
      int s = sbase + 4*lane + i;
      if(s>=olo && s<=ohi) dst[s] = a[i];
    }
    __syncthreads();
    if(wave==0){
      float acc = BIGN;
      for(int s = lane; s <= 800; s += 64){
        float x0 = af[s];
        float x1 = (s>=1)? af[s-1] : BIGN;
        float x2 = ((s&1) && s>=3)? af[s-2] : BIGN;
        float A1 = lse3b(x0,x1,x2);
        acc = lse2b(acc, A1 + ag[800-s]);
      }
#pragma unroll
      for(int o=32;o;o>>=1) acc = lse2b(acc, __shfl_xor(acc,o,64));
      if(lane==0) nll[b] = -((acc*L2) - (float)zs);
    }
  } else {
    if(wave) return;
    const int b = blockIdx.x - NB;
    const float* lp = logp + (size_t)b*TF*TT;
    unsigned char* cb = cmpb + (size_t)b*TF*64;
    int jc[7];
#pragma unroll
    for(int i=0;i<7;i++){ int j = 7*lane + i; jc[i] = (j < TT)? j : (TT-1); }
    float q[7];
#pragma unroll
    for(int i=0;i<7;i++) q[i] = BIGN;
    if(lane==0) q[0] = lp[0];
    float e0[7],e1[7],e2[7],e3[7];
    MPREF(e0,1); MPREF(e1,2); MPREF(e2,3); MPREF(e3,4);
    int t0 = 1;
    for(; t0 + 4 <= TF; t0 += 4){
      MAS_STEP(e0, t0);   MPREF(e0, t0+4);
      MAS_STEP(e1, t0+1); MPREF(e1, t0+5);
      MAS_STEP(e2, t0+2); MPREF(e2, t0+6);
      MAS_STEP(e3, t0+3); MPREF(e3, t0+7);
    }
    for(; t0<TF; t0++){
      float P[7];
      MPREF(P, t0);
      MAS_STEP(P, t0);
    }
    {
      float n1 = shup1(q[6]);
      u32 byte = 0;
      if(lane>0 && n1 >= q[0]) byte |= 1u;
      if(q[0] >= q[1]) byte |= 2u;
      if(q[1] >= q[2]) byte |= 4u;
      if(q[2] >= q[3]) byte |= 8u;
      if(q[3] >= q[4]) byte |= 16u;
      if(q[4] >= q[5]) byte |= 32u;
      if(q[5] >= q[6]) byte |= 64u;
      cb[(size_t)(TF-1)*64 + lane] = (unsigned char)byte;
    }
  }
}

// ---------------- MAS backtrack + ds + gather ----------------
__global__ __launch_bounds__(256) void masback_k(const unsigned char* __restrict__ cmpb,
    const float* __restrict__ logp, float* __restrict__ ds, float* __restrict__ gsum){
  const int b = blockIdx.x;
  const unsigned char* cb = cmpb + (size_t)b*TF*64;
  __shared__ unsigned char bits[500*64];
  __shared__ short Ash[TF];
  __shared__ int cnt[TT];
  __shared__ float ps[4];
  int a = TT-1;
  for(int ch=3; ch>=0; ch--){
    const int tlo = ch*500;
    __syncthreads();
    for(int i=threadIdx.x;i<8000;i+=256) ((u32*)bits)[i] = ((const u32*)(cb + (size_t)tlo*64))[i];
    __syncthreads();
    if(threadIdx.x==0){
      int thi = tlo + 499;
      if(ch==3){ Ash[TF-1] = (short)(TT-1); thi = TF-2; }
      for(int t=thi;t>=tlo;t--){
        if(a > 0){
          unsigned char w = bits[(t-tlo)*64 + a/7];
          a -= (int)((w >> (a%7)) & 1u);
        }
        Ash[t] = (short)a;
      }
    }
  }
  __syncthreads();
  for(int i=threadIdx.x;i<TT;i+=256) cnt[i]=0;
  __syncthreads();
  float part = 0.f;
  const float* lp = logp + (size_t)b*TF*TT;
  for(int t=threadIdx.x;t<TF;t+=256){
    int at = Ash[t];
    atomicAdd(&cnt[at], 1);
    part += lp[(size_t)t*TT + at];
  }
  __syncthreads();
  for(int i=threadIdx.x;i<TT;i+=256) ds[(size_t)b*TT + i] = (float)cnt[i];
  part = wsum(part);
  if((threadIdx.x&63)==0) ps[threadIdx.x>>6] = part;
  __syncthreads();
  if(threadIdx.x==0) gsum[b] = ps[0]+ps[1]+ps[2]+ps[3];
}

__global__ void final_k(const float* __restrict__ nll, const float* __restrict__ gsum, float* __restrict__ out){
  if(threadIdx.x==0 && blockIdx.x==0){
    float fs=0.f, bs=0.f;
    for(int b=0;b<NB;b++){ fs += nll[b] / (float)TT; bs += gsum[b] / (float)TF; }
    out[6400] = -(bs / (float)NB);   // bin_loss
    out[6401] = fs / (float)NB;      // forwardsum_loss
  }
}

extern "C" void kernel_launch(void* const* d_in, const int* in_sizes, int n_in,
                              void* d_out, int out_size, void* d_ws, size_t ws_size,
                              hipStream_t stream){
  const float* speech = (const float*)d_in[0];
  const float* txt    = (const float*)d_in[1];
  const float* tw1 = (const float*)d_in[4];
  const float* tb1 = (const float*)d_in[5];
  const float* tw2 = (const float*)d_in[6];
  const float* tb2 = (const float*)d_in[7];
  const float* fw1 = (const float*)d_in[8];
  const float* fb1 = (const float*)d_in[9];
  const float* fw2 = (const float*)d_in[10];
  const float* fb2 = (const float*)d_in[11];
  const float* fw3 = (const float*)d_in[12];
  const float* fb3 = (const float*)d_in[13];
  float* out  = (float*)d_out;
  float* ds   = out;                 // (16,400)
  float* logp = out + 6402;          // (16,2000,400) -- also conv scratch until score_mf
  char* ws = (char*)d_ws;
  double* lgt  = (double*)(ws + 0);
  double* rowA = (double*)(ws + 20480);
  double* colA = (double*)(ws + 36864);
  double* sA   = (double*)(ws + 40960);
  float*  nll  = (float*)(ws + 61440);
  float*  gsum = (float*)(ws + 61696);
  float*  Z2   = (float*)(ws + 65536);
  float*  fn2  = (float*)(ws + 196608);
  float*  tn2  = (float*)(ws + 327680);
  unsigned char* cmpb = (unsigned char*)(ws + 360448);
  u16*    th   = (u16*)(ws + 2408448);     // t_enc fp16 (16,400,256)   3.28MB
  u16*    fh   = (u16*)(ws + 8962048);     // f_enc fp16 (16,2000,256) 16.38MB
  if(ws_size < 41730048) return;

  // conv scratch inside the (dead until score_mf) logp region; 256B-aligned base
  char* lr = (char*)(((uintptr_t)logp + 255) & ~(uintptr_t)255);
  u16* inbfT = (u16*)lr;                    // (16,402,256)  3.29MB   [txt phase]
  u16* tout1 = (u16*)(lr + 4000000);        // (16,402,256)  3.29MB   [txt phase]
  u16* inbfA = (u16*)lr;                    // (16,2002,512) 32.80MB  [f phase 1; AFTER txt phase]
  u16* out2  = (u16*)lr;                    // (16,2002,256) 16.40MB  [f phase 3, after inbfA dead]
  u16* wbase = (u16*)(lr + 32900000);       // packs, 1.84MB, live all conv phases
  u16* fw1p = wbase;
  u16* fw2p = wbase + 393216;
  u16* fw3p = wbase + 589824;
  u16* tw1p = wbase + 655360;
  u16* tw2p = wbase + 851968;
  u16* out1  = (u16*)(lr + 34750000);       // (16,2002,256) 16.40MB

  k_lgt  <<<10,256,0,stream>>>(lgt);
  k_terms<<<10,256,0,stream>>>(lgt,rowA,colA,sA);

  prep1_k<<<2048,256,0,stream>>>(fw1,fw2,fw3,tw1,tw2, txt,
                                 fw1p,fw2p,fw3p,tw1p,tw2p, inbfT, tout1, out1);

  // txt path
  mfconv_k<256,3,true ,1><<<dim3(7,NB),256,0,stream>>>(inbfT, tw1p, tb1, tout1, TT);
  mfconv_k<256,1,false,2><<<dim3(7,NB),256,0,stream>>>(tout1, tw2p, tb2, th, TT);

  // f path (speech convert must run AFTER txt phase: inbfA overlaps inbfT/tout1)
  cvt_pad_k<<<4096,256,0,stream>>>(speech, inbfA, TF, 512);
  mfconv_k<512,3,true ,1><<<dim3(32,NB),256,0,stream>>>(inbfA, fw1p, fb1, out1, TF);
  zpad_k<<<32,256,0,stream>>>(out2, TF);               // after fconv1: inbfA region dead
  mfconv_k<256,3,true ,1><<<dim3(32,NB),256,0,stream>>>(out1, fw2p, fb2, out2, TF);
  mfconv_k<256,1,false,2><<<dim3(32,NB),256,0,stream>>>(out2, fw3p, fb3, fh, TF);

  norm2h_k<<<(NB*TF+NB*TT)/4,256,0,stream>>>(fh, th, fn2, tn2);

  score_mf<<<dim3(7,32,NB),256,0,stream>>>(fh, th, fn2, tn2, logp);
  softmax_prior_k<<<NB*TF,128,0,stream>>>(logp, rowA, colA, sA, Z2);

  scan_k<<<2*NB,512,0,stream>>>(logp, Z2, cmpb, nll);
  masback_k<<<NB,256,0,stream>>>(cmpb, logp, ds, gsum);
  final_k<<<1,64,0,stream>>>(nll, gsum, out);
}